// Round 3
// baseline (71.624 us; speedup 1.0000x reference)
//
#include <hip/hip_runtime.h>
#include <hip/hip_bf16.h>

#define LOG2E 1.4426950408889634f
#define C2    (2.0f * LOG2E)

static __device__ __forceinline__ float fast_exp2(float x) {
#if __has_builtin(__builtin_amdgcn_exp2f)
  return __builtin_amdgcn_exp2f(x);
#else
  return exp2f(x);
#endif
}
static __device__ __forceinline__ float fast_rcp(float x) {
#if __has_builtin(__builtin_amdgcn_rcpf)
  return __builtin_amdgcn_rcpf(x);
#else
  return 1.0f / x;
#endif
}

// ---------------------------------------------------------------------------
// Projections.  bz=0: qs[q][h] = C2 * queries@W_q  (row-major, coalesced)
//               bz=1: ks_p[b][h>>2][k][h&3] = C2 * keys@W_k  (packed for attn)
// 32(m) x 64(n) tile, 256 threads, 2x4 acc/thread.  A staged transposed in
// LDS (b64 reads); B (= W) read DIRECTLY from global (L1-resident 8KB/kc) —
// splits pipe pressure LDS||VMEM instead of all-LDS.
// ---------------------------------------------------------------------------
__global__ __launch_bounds__(256) void proj_kernel(
    const float* __restrict__ queries, const float* __restrict__ keys,
    const float* __restrict__ W_q,     const float* __restrict__ W_k,
    const int*   __restrict__ vlen,
    float* __restrict__ qs, float* __restrict__ ks_p)
{
  const int bz = blockIdx.z;
  const float* X = bz ? keys : queries;
  const float* W = bz ? W_k  : W_q;
  const int n0 = blockIdx.x * 64;
  const int m0 = blockIdx.y * 32;

  // masked key rows never matter downstream — skip whole 32-row tiles.
  if (bz == 1) {
    const int vl = vlen[m0 >> 8];
    if ((m0 & 255) >= vl) return;
  }

  const int t  = threadIdx.x;
  const int tx = t & 15, ty = t >> 4;

  __shared__ __align__(16) float Xs[32 * 34];   // [d][m], pad 34

  float4 acc0 = make_float4(0.f, 0.f, 0.f, 0.f);
  float4 acc1 = make_float4(0.f, 0.f, 0.f, 0.f);

  for (int kc = 0; kc < 8; ++kc) {
    {                                           // stage X 32x32 transposed
      int row = t >> 3, seg = t & 7;
      float4 v = *(const float4*)&X[(m0 + row) * 256 + kc * 32 + seg * 4];
      Xs[(seg * 4 + 0) * 34 + row] = v.x;
      Xs[(seg * 4 + 1) * 34 + row] = v.y;
      Xs[(seg * 4 + 2) * 34 + row] = v.z;
      Xs[(seg * 4 + 3) * 34 + row] = v.w;
    }
    __syncthreads();
    const float* Wp = &W[(kc * 32) * 256 + n0 + tx * 4];
#pragma unroll 8
    for (int kk = 0; kk < 32; ++kk) {
      float2 a  = *(const float2*)&Xs[kk * 34 + ty * 2];
      float4 bv = *(const float4*)(Wp + kk * 256);
      acc0.x = fmaf(a.x, bv.x, acc0.x);
      acc0.y = fmaf(a.x, bv.y, acc0.y);
      acc0.z = fmaf(a.x, bv.z, acc0.z);
      acc0.w = fmaf(a.x, bv.w, acc0.w);
      acc1.x = fmaf(a.y, bv.x, acc1.x);
      acc1.y = fmaf(a.y, bv.y, acc1.y);
      acc1.z = fmaf(a.y, bv.z, acc1.z);
      acc1.w = fmaf(a.y, bv.w, acc1.w);
    }
    __syncthreads();
  }

  if (bz == 0) {
    float4 o0 = make_float4(acc0.x * C2, acc0.y * C2, acc0.z * C2, acc0.w * C2);
    float4 o1 = make_float4(acc1.x * C2, acc1.y * C2, acc1.z * C2, acc1.w * C2);
    *(float4*)&qs[(m0 + ty * 2 + 0) * 256 + n0 + tx * 4] = o0;
    *(float4*)&qs[(m0 + ty * 2 + 1) * 256 + n0 + tx * 4] = o1;
  } else {
    // packed: ks_p flat idx = ((b*64 + h4)*256 + k)*4 + (h&3);  h4 = n0/4+tx
    const int b  = m0 >> 8;
    const int kl = (m0 & 255) + ty * 2;
    float* base = &ks_p[((b * 64 + (n0 >> 2) + tx) * 256 + kl) * 4];
    base[0] = acc0.x * C2; base[1] = acc0.y * C2;
    base[2] = acc0.z * C2; base[3] = acc0.w * C2;
    base[4] = acc1.x * C2; base[5] = acc1.y * C2;
    base[6] = acc1.z * C2; base[7] = acc1.w * C2;
  }
}

// ---------------------------------------------------------------------------
// Fused scores + softmax + PV.
// Grid: 512 blocks = B(8) x Qtiles(64).  Block: 512 thr = 8 waves
//   = 4 q-rows (ql) x 2 h-halves (hh).
// Score inner loop: NO LDS except 2 broadcast b128 reads per 4h; ks read as
// coalesced b128 from ks_p (L2-resident, 2 MB).  64-granular uniform k-mask.
// Then: cross-wave partial-score reduce -> softmax -> 8-way k-split PV
// (V coalesced b128 from L2) -> LDS reduce.
// ---------------------------------------------------------------------------
__global__ __launch_bounds__(512, 4) void attn_kernel(
    const float* __restrict__ qs, const float* __restrict__ ks_p,
    const float* __restrict__ values, const int* __restrict__ vlen,
    const float* __restrict__ w_v, float* __restrict__ out)
{
  const int t    = threadIdx.x;
  const int lane = t & 63;
  const int w    = t >> 6;
  const int ql   = w >> 1;                 // 0..3
  const int hh   = w & 1;                  // 0..1
  const int bx   = blockIdx.x;
  const int b    = bx >> 6;
  const int q0   = (bx & 63) * 4;

  __shared__ __align__(16) float part[8][4][256];   // 32 KB; [0..2KB) doubles as sc_part[4][2][256]
  __shared__ __align__(16) float p_lds[4][256];
  __shared__ __align__(16) float qs_lds[4][256];
  __shared__ __align__(16) float w2_lds[256];
  __shared__ float red_max[4][2];
  __shared__ float red_sum[4][2];

  if (t < 256) {
    w2_lds[t] = -2.0f * w_v[t];
    int q = t >> 6, seg = t & 63;
    *(float4*)&qs_lds[q][seg * 4] =
        *(const float4*)&qs[(b * 256 + q0 + q) * 256 + seg * 4];
  }
  __syncthreads();

  // Wsum = sum(w_v) = -0.5*sum(w2); every wave computes it
  float s0 = w2_lds[lane] + w2_lds[lane + 64] + w2_lds[lane + 128] + w2_lds[lane + 192];
#pragma unroll
  for (int off = 32; off; off >>= 1) s0 += __shfl_xor(s0, off);
  const float Wsum = -0.5f * s0;

  const int vl = vlen[b];
  const int nj = (vl + 63) >> 6;

  float sc[4];
#pragma unroll
  for (int j = 0; j < 4; ++j) sc[j] = (hh == 0) ? Wsum : 0.f;

  const float* kp_base = ks_p + (size_t)(b * 64) * 1024 + lane * 4;
  for (int h4i = 0; h4i < 32; ++h4i) {
    const int h4g = hh * 32 + h4i;
    float4 qv = *(const float4*)&qs_lds[ql][h4g * 4];   // broadcast
    float4 wv = *(const float4*)&w2_lds[h4g * 4];       // broadcast
    const float* kp = kp_base + h4g * 1024;
#pragma unroll
    for (int j = 0; j < 4; ++j) {
      if (j < nj) {                                     // block-uniform skip
        float4 kv = *(const float4*)(kp + j * 256);     // 4 h of k=j*64+lane
        sc[j] = fmaf(wv.x, fast_rcp(fast_exp2(qv.x + kv.x) + 1.f), sc[j]);
        sc[j] = fmaf(wv.y, fast_rcp(fast_exp2(qv.y + kv.y) + 1.f), sc[j]);
        sc[j] = fmaf(wv.z, fast_rcp(fast_exp2(qv.z + kv.z) + 1.f), sc[j]);
        sc[j] = fmaf(wv.w, fast_rcp(fast_exp2(qv.w + kv.w) + 1.f), sc[j]);
      }
    }
  }

  float* sc_part = &part[0][0][0];         // [4 q][2 hh][256 k]
#pragma unroll
  for (int j = 0; j < 4; ++j)
    sc_part[(ql * 2 + hh) * 256 + j * 64 + lane] = sc[j];
  __syncthreads();

  // softmax: wave (ql,hh) handles k-range [hh*128, hh*128+128)
  const int ks0 = hh * 128;
  float sv[2];
#pragma unroll
  for (int j2 = 0; j2 < 2; ++j2) {
    int k = ks0 + j2 * 64 + lane;
    float s = sc_part[(ql * 2 + 0) * 256 + k] + sc_part[(ql * 2 + 1) * 256 + k];
    sv[j2] = (k >= vl) ? -1000000.0f : s;
  }
  float mx = fmaxf(sv[0], sv[1]);
#pragma unroll
  for (int off = 32; off; off >>= 1) mx = fmaxf(mx, __shfl_xor(mx, off));
  if (lane == 0) red_max[ql][hh] = mx;
  __syncthreads();
  mx = fmaxf(red_max[ql][0], red_max[ql][1]);
  float ps = 0.f;
#pragma unroll
  for (int j2 = 0; j2 < 2; ++j2) {
    float p = fast_exp2((sv[j2] - mx) * LOG2E);
    p_lds[ql][ks0 + j2 * 64 + lane] = p;
    ps += p;
  }
#pragma unroll
  for (int off = 32; off; off >>= 1) ps += __shfl_xor(ps, off);
  if (lane == 0) red_sum[ql][hh] = ps;
  __syncthreads();                          // p ready; part[] free to overwrite

  // PV: wave w owns k-slice [w*32, w*32+32); uniform skip if fully masked
  const int nw = (vl + 31) >> 5;
  if (w < nw) {
    const int kb = w * 32;
    const int nk = min(32, vl - kb);
    float4 acc[4];
#pragma unroll
    for (int q = 0; q < 4; ++q) acc[q] = make_float4(0.f, 0.f, 0.f, 0.f);
    const float* Vp = values + ((size_t)(b * 256 + kb)) * 256 + lane * 4;
    for (int kk = 0; kk < nk; ++kk) {
      float4 v = *(const float4*)(Vp + kk * 256);
#pragma unroll
      for (int q = 0; q < 4; ++q) {
        float pk = p_lds[q][kb + kk];
        acc[q].x = fmaf(pk, v.x, acc[q].x);
        acc[q].y = fmaf(pk, v.y, acc[q].y);
        acc[q].z = fmaf(pk, v.z, acc[q].z);
        acc[q].w = fmaf(pk, v.w, acc[q].w);
      }
    }
#pragma unroll
    for (int q = 0; q < 4; ++q)
      *(float4*)&part[w][q][lane * 4] = acc[q];
  }
  __syncthreads();

  // final reduce: 512 thr x 2 -> 4q x 256d outputs
#pragma unroll
  for (int rep = 0; rep < 2; ++rep) {
    int o = t + rep * 512;
    int q = o >> 8, d = o & 255;
    float s = 0.f;
    for (int ww = 0; ww < nw; ++ww) s += part[ww][q][d];
    float rsum = red_sum[q][0] + red_sum[q][1];
    out[(b * 256 + q0 + q) * 256 + d] = s * fast_rcp(rsum);
  }
}

extern "C" void kernel_launch(void* const* d_in, const int* in_sizes, int n_in,
                              void* d_out, int out_size, void* d_ws, size_t ws_size,
                              hipStream_t stream) {
  const float* queries = (const float*)d_in[0];
  const float* keys    = (const float*)d_in[1];
  const float* values  = (const float*)d_in[2];
  const int*   vlenp   = (const int*)d_in[3];
  const float* W_q     = (const float*)d_in[4];
  const float* W_k     = (const float*)d_in[5];
  const float* w_v     = (const float*)d_in[6];
  float* out = (float*)d_out;

  float* qs   = (float*)d_ws;               // 2048*256 f32 = 2 MiB
  float* ks_p = qs + 2048 * 256;            // 2 MiB, packed [b][h/4][k][4]

  dim3 pgrid(4, 64, 2);
  proj_kernel<<<pgrid, 256, 0, stream>>>(queries, keys, W_q, W_k, vlenp, qs, ks_p);
  attn_kernel<<<512, 512, 0, stream>>>(qs, ks_p, values, vlenp, w_v, out);
}

// Round 4
// 49.947 us; speedup vs baseline: 1.4340x; 1.4340x over previous
//
#include <hip/hip_runtime.h>
#include <hip/hip_bf16.h>

#define LOG2E 1.4426950408889634f
#define C2    (2.0f * LOG2E)

static __device__ __forceinline__ float fast_exp2(float x) {
#if __has_builtin(__builtin_amdgcn_exp2f)
  return __builtin_amdgcn_exp2f(x);
#else
  return exp2f(x);
#endif
}
static __device__ __forceinline__ float fast_rcp(float x) {
#if __has_builtin(__builtin_amdgcn_rcpf)
  return __builtin_amdgcn_rcpf(x);
#else
  return 1.0f / x;
#endif
}

// ---------------------------------------------------------------------------
// Projections (round-2 structure: Xs transposed + Ws both in LDS).
// bz=0: qs[q][h] = C2 * queries@W_q (row-major)
// bz=1: ks_p[((b*64 + h/4)*256 + k)*4 + h%4] = C2 * keys@W_k (packed)
// 32(m) x 64(n) tile, 256 threads, 2x4 acc/thread, K-chunks of 32.
// ---------------------------------------------------------------------------
__global__ __launch_bounds__(256) void proj_kernel(
    const float* __restrict__ queries, const float* __restrict__ keys,
    const float* __restrict__ W_q,     const float* __restrict__ W_k,
    const int*   __restrict__ vlen,
    float* __restrict__ qs, float* __restrict__ ks_p)
{
  const int bz = blockIdx.z;
  const float* X = bz ? keys : queries;
  const float* W = bz ? W_k  : W_q;
  const int n0 = blockIdx.x * 64;
  const int m0 = blockIdx.y * 32;

  if (bz == 1) {                      // masked key rows: skip whole tiles
    const int vl = vlen[m0 >> 8];
    if ((m0 & 255) >= vl) return;
  }

  const int t  = threadIdx.x;
  const int tx = t & 15, ty = t >> 4;

  __shared__ __align__(16) float Xs[32 * 34];   // [d][m]
  __shared__ __align__(16) float Ws[32 * 68];   // [d][n]

  float4 acc0 = make_float4(0.f, 0.f, 0.f, 0.f);
  float4 acc1 = make_float4(0.f, 0.f, 0.f, 0.f);

  for (int kc = 0; kc < 8; ++kc) {
    {                                           // stage X 32x32 transposed
      int row = t >> 3, seg = t & 7;
      float4 v = *(const float4*)&X[(m0 + row) * 256 + kc * 32 + seg * 4];
      Xs[(seg * 4 + 0) * 34 + row] = v.x;
      Xs[(seg * 4 + 1) * 34 + row] = v.y;
      Xs[(seg * 4 + 2) * 34 + row] = v.z;
      Xs[(seg * 4 + 3) * 34 + row] = v.w;
    }
#pragma unroll
    for (int m = 0; m < 2; ++m) {               // stage W 32x64
      int idx = t + 256 * m;
      int row = idx >> 4, seg = idx & 15;
      *(float4*)&Ws[row * 68 + seg * 4] =
          *(const float4*)&W[(kc * 32 + row) * 256 + n0 + seg * 4];
    }
    __syncthreads();
#pragma unroll
    for (int kk = 0; kk < 32; ++kk) {
      float2 a  = *(const float2*)&Xs[kk * 34 + ty * 2];
      float4 bv = *(const float4*)&Ws[kk * 68 + tx * 4];
      acc0.x = fmaf(a.x, bv.x, acc0.x);
      acc0.y = fmaf(a.x, bv.y, acc0.y);
      acc0.z = fmaf(a.x, bv.z, acc0.z);
      acc0.w = fmaf(a.x, bv.w, acc0.w);
      acc1.x = fmaf(a.y, bv.x, acc1.x);
      acc1.y = fmaf(a.y, bv.y, acc1.y);
      acc1.z = fmaf(a.y, bv.z, acc1.z);
      acc1.w = fmaf(a.y, bv.w, acc1.w);
    }
    __syncthreads();
  }

  if (bz == 0) {
    float4 o0 = make_float4(acc0.x * C2, acc0.y * C2, acc0.z * C2, acc0.w * C2);
    float4 o1 = make_float4(acc1.x * C2, acc1.y * C2, acc1.z * C2, acc1.w * C2);
    *(float4*)&qs[(m0 + ty * 2 + 0) * 256 + n0 + tx * 4] = o0;
    *(float4*)&qs[(m0 + ty * 2 + 1) * 256 + n0 + tx * 4] = o1;
  } else {
    const int b  = m0 >> 8;
    const int kl = (m0 & 255) + ty * 2;
    float* base = &ks_p[((size_t)(b * 64 + (n0 >> 2) + tx) * 256 + kl) * 4];
    float4 o0 = make_float4(acc0.x * C2, acc0.y * C2, acc0.z * C2, acc0.w * C2);
    float4 o1 = make_float4(acc1.x * C2, acc1.y * C2, acc1.z * C2, acc1.w * C2);
    *(float4*)&base[0] = o0;     // k = kl,   h = 4*h4..+3
    *(float4*)&base[4] = o1;     // k = kl+1
  }
}

// ---------------------------------------------------------------------------
// Fused scores + softmax + PV.
// Grid: 1024 blocks = B(8) x Qtiles(128); co-resident blocks (stride 256)
// span 4 different batches -> work balance.  Block: 256 thr = 4 waves
//   = 2 q-rows (ql) x 2 h-halves (hh).
// Score loop: registers-only, ks read as coalesced b128 from packed ks_p
// (L2-resident 2 MB) with depth-1 software prefetch (next h4's 4 loads
// issued before current compute -> 352cy compute hides L2 latency).
// Then cross-wave score reduce -> softmax -> 4-way k-split PV -> reduce.
// ---------------------------------------------------------------------------
__global__ __launch_bounds__(256, 4) void attn_kernel(
    const float* __restrict__ qs, const float* __restrict__ ks_p,
    const float* __restrict__ values, const int* __restrict__ vlen,
    const float* __restrict__ w_v, float* __restrict__ out)
{
  const int t    = threadIdx.x;
  const int lane = t & 63;
  const int w    = t >> 6;                 // 0..3
  const int ql   = w >> 1;                 // 0..1
  const int hh   = w & 1;                  // 0..1
  const int bx   = blockIdx.x;
  const int b    = bx >> 7;
  const int q0   = (bx & 127) * 2;

  __shared__ __align__(16) float part[4][2][256];  // 8 KB; front 4 KB = sc_part[2][2][256]
  __shared__ __align__(16) float p_lds[2][256];
  __shared__ __align__(16) float qs_lds[2][256];
  __shared__ __align__(16) float w2_lds[256];
  __shared__ float red_max[2][2];
  __shared__ float red_sum[2][2];

  w2_lds[t] = -2.0f * w_v[t];
  if (t < 128) {
    int q = t >> 6, seg = t & 63;
    *(float4*)&qs_lds[q][seg * 4] =
        *(const float4*)&qs[(b * 256 + q0 + q) * 256 + seg * 4];
  }
  __syncthreads();

  // Wsum = sum(w_v) = -0.5 * sum(w2)
  float s0 = w2_lds[lane] + w2_lds[lane + 64] + w2_lds[lane + 128] + w2_lds[lane + 192];
#pragma unroll
  for (int off = 32; off; off >>= 1) s0 += __shfl_xor(s0, off);
  const float Wsum = -0.5f * s0;

  const int vl = vlen[b];
  const int nj = (vl + 63) >> 6;           // active 64-wide k groups

  float sc[4];
#pragma unroll
  for (int j = 0; j < 4; ++j) sc[j] = (hh == 0) ? Wsum : 0.f;

  // score loop with depth-1 register prefetch
  const float* kp0 = ks_p + (size_t)b * 65536 + (size_t)hh * 32768 + lane * 4;
  float4 kv[4], kvn[4] = {};
#pragma unroll
  for (int j = 0; j < 4; ++j)
    kv[j] = (j < nj) ? *(const float4*)(kp0 + j * 256)
                     : make_float4(0.f, 0.f, 0.f, 0.f);

  for (int h4i = 0; h4i < 32; ++h4i) {
    const float* kpn = kp0 + (size_t)(h4i + 1) * 1024;
    const bool pf = (h4i < 31);
#pragma unroll
    for (int j = 0; j < 4; ++j)
      if (pf && j < nj) kvn[j] = *(const float4*)(kpn + j * 256);

    const int h4g = hh * 32 + h4i;
    float4 qv = *(const float4*)&qs_lds[ql][h4g * 4];   // broadcast
    float4 wv = *(const float4*)&w2_lds[h4g * 4];       // broadcast
#pragma unroll
    for (int j = 0; j < 4; ++j) {
      if (j < nj) {
        sc[j] = fmaf(wv.x, fast_rcp(fast_exp2(qv.x + kv[j].x) + 1.f), sc[j]);
        sc[j] = fmaf(wv.y, fast_rcp(fast_exp2(qv.y + kv[j].y) + 1.f), sc[j]);
        sc[j] = fmaf(wv.z, fast_rcp(fast_exp2(qv.z + kv[j].z) + 1.f), sc[j]);
        sc[j] = fmaf(wv.w, fast_rcp(fast_exp2(qv.w + kv[j].w) + 1.f), sc[j]);
      }
    }
#pragma unroll
    for (int j = 0; j < 4; ++j) kv[j] = kvn[j];
  }

  float* sc_part = &part[0][0][0];         // [2 q][2 hh][256 k]
#pragma unroll
  for (int j = 0; j < 4; ++j)
    sc_part[(ql * 2 + hh) * 256 + j * 64 + lane] = sc[j];
  __syncthreads();

  // softmax: wave (ql,hh) handles q=ql, k-range [hh*128, hh*128+128)
  const int ks0 = hh * 128;
  float sv[2];
#pragma unroll
  for (int j2 = 0; j2 < 2; ++j2) {
    int k = ks0 + j2 * 64 + lane;
    float s = sc_part[(ql * 2 + 0) * 256 + k] + sc_part[(ql * 2 + 1) * 256 + k];
    sv[j2] = (k >= vl) ? -1000000.0f : s;
  }
  float mx = fmaxf(sv[0], sv[1]);
#pragma unroll
  for (int off = 32; off; off >>= 1) mx = fmaxf(mx, __shfl_xor(mx, off));
  if (lane == 0) red_max[ql][hh] = mx;
  __syncthreads();
  mx = fmaxf(red_max[ql][0], red_max[ql][1]);
  float ps = 0.f;
#pragma unroll
  for (int j2 = 0; j2 < 2; ++j2) {
    float p = fast_exp2((sv[j2] - mx) * LOG2E);
    p_lds[ql][ks0 + j2 * 64 + lane] = p;
    ps += p;
  }
#pragma unroll
  for (int off = 32; off; off >>= 1) ps += __shfl_xor(ps, off);
  if (lane == 0) red_sum[ql][hh] = ps;
  __syncthreads();                          // sc_part reads done; p ready

  // PV: wave w owns k-slice [w*64, w*64+64)
  if (w < nj) {
    const int kb = w * 64;
    const int nk = min(64, vl - kb);
    float4 acc[2];
    acc[0] = make_float4(0.f, 0.f, 0.f, 0.f);
    acc[1] = make_float4(0.f, 0.f, 0.f, 0.f);
    const float* Vp = values + (size_t)(b * 256 + kb) * 256 + lane * 4;
#pragma unroll 4
    for (int kk = 0; kk < nk; ++kk) {
      float4 v = *(const float4*)(Vp + (size_t)kk * 256);
#pragma unroll
      for (int q = 0; q < 2; ++q) {
        float pk = p_lds[q][kb + kk];
        acc[q].x = fmaf(pk, v.x, acc[q].x);
        acc[q].y = fmaf(pk, v.y, acc[q].y);
        acc[q].z = fmaf(pk, v.z, acc[q].z);
        acc[q].w = fmaf(pk, v.w, acc[q].w);
      }
    }
#pragma unroll
    for (int q = 0; q < 2; ++q)
      *(float4*)&part[w][q][lane * 4] = acc[q];
  }
  __syncthreads();

  // final reduce: 256 thr x 2 -> 2q x 256d outputs
#pragma unroll
  for (int rep = 0; rep < 2; ++rep) {
    int o = t + rep * 256;
    int q = o >> 8, d = o & 255;
    float s = 0.f;
    for (int ww = 0; ww < nj; ++ww) s += part[ww][q][d];
    float rsum = red_sum[q][0] + red_sum[q][1];
    out[(b * 256 + q0 + q) * 256 + d] = s * fast_rcp(rsum);
  }
}

extern "C" void kernel_launch(void* const* d_in, const int* in_sizes, int n_in,
                              void* d_out, int out_size, void* d_ws, size_t ws_size,
                              hipStream_t stream) {
  const float* queries = (const float*)d_in[0];
  const float* keys    = (const float*)d_in[1];
  const float* values  = (const float*)d_in[2];
  const int*   vlenp   = (const int*)d_in[3];
  const float* W_q     = (const float*)d_in[4];
  const float* W_k     = (const float*)d_in[5];
  const float* w_v     = (const float*)d_in[6];
  float* out = (float*)d_out;

  float* qs   = (float*)d_ws;               // 2 MiB, row-major [m][256]
  float* ks_p = qs + 2048 * 256;            // 2 MiB, packed [b][h/4][k][4]

  dim3 pgrid(4, 64, 2);
  proj_kernel<<<pgrid, 256, 0, stream>>>(queries, keys, W_q, W_k, vlenp, qs, ks_p);
  attn_kernel<<<1024, 256, 0, stream>>>(qs, ks_p, values, vlenp, w_v, out);
}